// Round 15
// baseline (283.011 us; speedup 1.0000x reference)
//
#include <hip/hip_runtime.h>
#include <hip/hip_bf16.h>
#include <stdint.h>

typedef __attribute__((ext_vector_type(8))) short short8;
typedef __attribute__((ext_vector_type(4))) short short4v;
typedef __attribute__((ext_vector_type(4))) float f32x4;
typedef __attribute__((ext_vector_type(16))) float f32x16;

#define LSEQ 4096
#define DMODEL 1024
#define NHEAD 8
#define HDIM 128
#define MTOT 8192
#define NQKV 3072

__device__ __forceinline__ unsigned short f2bf(float f){
  unsigned u = __float_as_uint(f);
  u += 0x7fffu + ((u >> 16) & 1u);
  return (unsigned short)(u >> 16);
}
__device__ __forceinline__ float bf2f(unsigned short h){
  return __uint_as_float(((unsigned)h) << 16);
}

typedef const __attribute__((address_space(1))) void* gas_ptr;
typedef __attribute__((address_space(3))) void* las_ptr;
__device__ __forceinline__ void gload_lds16(const void* g, void* l){
  __builtin_amdgcn_global_load_lds((gas_ptr)(uintptr_t)g,
                                   (las_ptr)(unsigned)(uintptr_t)l, 16, 0, 0);
}

// ---------------- fp32 -> bf16 cast (8 elems/thread) ----------------
__global__ __launch_bounds__(256) void k_cvt(const float* __restrict__ in,
                                             unsigned short* __restrict__ out, int n8){
  int i = blockIdx.x*256 + threadIdx.x;
  if (i >= n8) return;
  const float4* p = (const float4*)in + (size_t)i*2;
  float4 a = p[0], b = p[1];
  short8 r;
  r[0]=(short)f2bf(a.x); r[1]=(short)f2bf(a.y); r[2]=(short)f2bf(a.z); r[3]=(short)f2bf(a.w);
  r[4]=(short)f2bf(b.x); r[5]=(short)f2bf(b.y); r[6]=(short)f2bf(b.z); r[7]=(short)f2bf(b.w);
  *(short8*)(out + (size_t)i*8) = r;
}

// ---------------- fp32 [R][C] -> bf16 transposed [C][R] ----------------
__global__ __launch_bounds__(256) void k_transpose_cvt(const float* __restrict__ in,
                                                       unsigned short* __restrict__ out,
                                                       int R, int C){
  __shared__ unsigned short tile[32][33];
  int c0 = blockIdx.x*32, r0 = blockIdx.y*32;
  int tx = threadIdx.x & 31, ty = threadIdx.x >> 5;   // 32 x 8
  #pragma unroll
  for (int i=0;i<32;i+=8)
    tile[ty+i][tx] = f2bf(in[(size_t)(r0+ty+i)*C + c0+tx]);
  __syncthreads();
  #pragma unroll
  for (int i=0;i<32;i+=8)
    out[(size_t)(c0+ty+i)*R + r0+tx] = tile[tx][ty+i];
}

// ---------------- bf16 V -> V^T per head: vT[bh][d][l] ----------------
__global__ __launch_bounds__(256) void k_vT(const unsigned short* __restrict__ qkv,
                                            unsigned short* __restrict__ vT){
  __shared__ unsigned short tile[32][33];
  int bh = blockIdx.z; int b = bh >> 3, h = bh & 7;
  int l0 = blockIdx.x*32, d0 = blockIdx.y*32;
  const unsigned short* src = qkv + (size_t)b*LSEQ*NQKV + 2*DMODEL + h*HDIM;
  int tx = threadIdx.x & 31, ty = threadIdx.x >> 5;   // 32 x 8
  #pragma unroll
  for (int i=0;i<32;i+=8)
    tile[ty+i][tx] = src[(size_t)(l0+ty+i)*NQKV + d0+tx];
  __syncthreads();
  unsigned short* dst = vT + ((size_t)bh*HDIM + d0)*LSEQ + l0;
  #pragma unroll
  for (int i=0;i<32;i+=8)
    dst[(size_t)(ty+i)*LSEQ + tx] = tile[tx][ty+i];
}

// ---------------- bf16 GEMM: C[M][N] = A[M][K] * Bt[N][K]^T + bias ----------------
// XCD-aware bijective block swizzle (grid size must be %8==0: 1536 and 512 are)
template<int OUT_BF16>
__global__ __launch_bounds__(256) void k_gemm_bt(const unsigned short* __restrict__ A,
                                                 const unsigned short* __restrict__ Bt,
                                                 const float* __restrict__ bias,
                                                 void* __restrict__ Cout,
                                                 int M, int N, int K){
  __shared__ unsigned short As[128*64];
  __shared__ unsigned short Bs[128*64];
  int tid = threadIdx.x, lane = tid & 63, wave = tid >> 6;
  int wm = wave >> 1, wn = wave & 1;
  // XCD swizzle: contiguous chunks of the linear id land on one XCD
  int nbx = N >> 7;
  int nwg = nbx * (M >> 7);
  int id  = blockIdx.y * nbx + blockIdx.x;
  int cpx = nwg >> 3;
  int swz = (id & 7) * cpx + (id >> 3);
  int m0 = (swz / nbx) * 128, n0 = (swz % nbx) * 128;
  f32x4 zero = {0.f,0.f,0.f,0.f};
  f32x4 acc[4][4];
  #pragma unroll
  for (int mi=0;mi<4;++mi)
    #pragma unroll
    for (int ni=0;ni<4;++ni) acc[mi][ni] = zero;

  int srow = lane >> 3;
  int soffb = (lane & 7) * 16;
  int scol = (soffb ^ (srow << 4)) >> 1;
  int cg = lane >> 4, cl = lane & 15;

  int nkt = K >> 6;
  for (int kt = 0; kt < nkt; ++kt){
    if (kt) __syncthreads();
    int kbase = kt*64;
    #pragma unroll
    for (int j=0;j<4;++j){
      int ch = wave*4 + j;
      int row = ch*8 + srow;
      gload_lds16(A  + (size_t)(m0+row)*K + kbase + scol, (char*)As + ch*1024);
      gload_lds16(Bt + (size_t)(n0+row)*K + kbase + scol, (char*)Bs + ch*1024);
    }
    __syncthreads();

    short8 af[4][2], bf[4][2];
    #pragma unroll
    for (int mi=0;mi<4;++mi){
      int row = wm*64 + mi*16 + cl;
      int key = (row & 7) << 4;
      #pragma unroll
      for (int kk=0;kk<2;++kk)
        af[mi][kk] = *(const short8*)((const char*)As + row*128 + ((kk*64 + cg*16) ^ key));
    }
    #pragma unroll
    for (int ni=0;ni<4;++ni){
      int row = wn*64 + ni*16 + cl;
      int key = (row & 7) << 4;
      #pragma unroll
      for (int kk=0;kk<2;++kk)
        bf[ni][kk] = *(const short8*)((const char*)Bs + row*128 + ((kk*64 + cg*16) ^ key));
    }
    #pragma unroll
    for (int kk=0;kk<2;++kk)
      #pragma unroll
      for (int mi=0;mi<4;++mi)
        #pragma unroll
        for (int ni=0;ni<4;++ni)
          acc[mi][ni] = __builtin_amdgcn_mfma_f32_16x16x32_bf16(af[mi][kk], bf[ni][kk], acc[mi][ni], 0,0,0);
  }

  #pragma unroll
  for (int ni=0;ni<4;++ni){
    int col = n0 + wn*64 + ni*16 + cl;
    float bv = bias[col];
    #pragma unroll
    for (int mi=0;mi<4;++mi){
      int r = m0 + wm*64 + mi*16 + cg*4;
      #pragma unroll
      for (int i=0;i<4;++i){
        float v = acc[mi][ni][i] + bv;
        if (OUT_BF16) ((unsigned short*)Cout)[(size_t)(r+i)*N + col] = f2bf(v);
        else          ((float*)Cout)[(size_t)(r+i)*N + col] = v;
      }
    }
  }
}

// ---------------- fused RMSNorm(q,k) + interleaved RoPE ----------------
// k additionally pre-scaled by K2 = log2(e)/sqrt(128): attention then computes
// P = exp2(S) directly (softmax scale folded into K; q*k relative error unchanged)
__global__ __launch_bounds__(256) void k_norm_rope(unsigned short* __restrict__ qkv,
                                                   const float* __restrict__ fcos,
                                                   const float* __restrict__ fsin,
                                                   const float* __restrict__ gq,
                                                   const float* __restrict__ gk){
  int bl = blockIdx.x;
  int l = bl & (LSEQ-1);
  int t = threadIdx.x;
  unsigned short* row = qkv + (size_t)bl * NQKV;
  int d0 = t*4;
  short4v qv = *(short4v*)(row + d0);
  short4v kv = *(short4v*)(row + DMODEL + d0);
  float q[4], k[4];
  #pragma unroll
  for (int j=0;j<4;++j){ q[j] = bf2f((unsigned short)qv[j]); k[j] = bf2f((unsigned short)kv[j]); }
  float sq = q[0]*q[0]+q[1]*q[1]+q[2]*q[2]+q[3]*q[3];
  float sk = k[0]*k[0]+k[1]*k[1]+k[2]*k[2]+k[3]*k[3];
  #pragma unroll
  for (int o=32;o;o>>=1){ sq += __shfl_xor(sq,o); sk += __shfl_xor(sk,o); }
  __shared__ float red[8];
  int lane = t & 63, wv = t >> 6;
  if (!lane){ red[wv] = sq; red[4+wv] = sk; }
  __syncthreads();
  sq = red[0]+red[1]+red[2]+red[3];
  sk = red[4]+red[5]+red[6]+red[7];
  const float K2 = 0.12753568849800323f;    // (1/sqrt(128)) * log2(e)
  float rq = rsqrtf(sq*(1.f/1024.f) + 1e-6f);
  float rk = rsqrtf(sk*(1.f/1024.f) + 1e-6f) * K2;
  int hd = d0 & (HDIM-1);
  int fi = (l << 6) + (hd >> 1);
  float c0 = fcos[fi], s0 = fsin[fi], c1 = fcos[fi+1], s1 = fsin[fi+1];
  {
    float x1 = q[0]*rq*gq[d0],   x2 = q[1]*rq*gq[d0+1];
    float x3 = q[2]*rq*gq[d0+2], x4 = q[3]*rq*gq[d0+3];
    short4v qo;
    qo[0]=(short)f2bf(x1*c0 - x2*s0); qo[1]=(short)f2bf(x1*s0 + x2*c0);
    qo[2]=(short)f2bf(x3*c1 - x4*s1); qo[3]=(short)f2bf(x3*s1 + x4*c1);
    *(short4v*)(row + d0) = qo;
  }
  {
    float x1 = k[0]*rk*gk[d0],   x2 = k[1]*rk*gk[d0+1];
    float x3 = k[2]*rk*gk[d0+2], x4 = k[3]*rk*gk[d0+3];
    short4v ko;
    ko[0]=(short)f2bf(x1*c0 - x2*s0); ko[1]=(short)f2bf(x1*s0 + x2*c0);
    ko[2]=(short)f2bf(x3*c1 - x4*s1); ko[3]=(short)f2bf(x3*s1 + x4*c1);
    *(short4v*)(row + DMODEL + d0) = ko;
  }
}

// ---------------- flash attention v14: static-max softmax with K2 pre-folded
// into K (P = exp2(S) directly), 4 waves x 32 q-rows, 32x32x16, in-register P,
// MFMA-ones row-sum, strength-reduced staging pointers ----------------
__global__ __launch_bounds__(256, 2) void k_attn(const unsigned short* __restrict__ qkv,
                                                 const unsigned short* __restrict__ vT,
                                                 unsigned short* __restrict__ o){
  __shared__ unsigned short Ks[2][64*128];   // 32KB, rows 256B, XOR-swizzled content
  __shared__ unsigned short VTs[2][128*64];  // 32KB, rows=d 128B, XOR-swizzled content
  int bh = blockIdx.y; int b = bh >> 3, h = bh & 7;
  int q0 = blockIdx.x * 128;
  int tid = threadIdx.x, lane = tid & 63, wave = tid >> 6;
  int ql = lane & 31, hf = lane >> 5;
  const unsigned short* base = qkv + (size_t)b*LSEQ*NQKV + h*HDIM;
  const unsigned short* kgl = base + DMODEL;
  const unsigned short* vtg = vT + (size_t)bh*HDIM*LSEQ;   // [d][l]

  // Q B-frags: lane holds Q[q = ql][d = st*16 + hf*8 + e], st=0..7
  short8 qf[8];
  {
    const unsigned short* qr = base + (size_t)(q0 + wave*32 + ql)*NQKV + hf*8;
    #pragma unroll
    for (int st=0;st<8;++st) qf[st] = *(const short8*)(qr + st*16);
  }
  short8 ones;
  #pragma unroll
  for (int j=0;j<8;++j) ones[j] = (short)0x3F80;   // bf16 1.0

  f32x16 z16 = {0.f};
  f32x16 acc[4];
  acc[0]=z16; acc[1]=z16; acc[2]=z16; acc[3]=z16;
  f32x16 accl = z16;                         // row-sums l (MFMA-ones)

  int key = (ql & 7) << 4;

  int v_dl   = lane >> 3;                           // VT: d within 8-row chunk
  int v_srcb = ((lane & 7)*16) ^ (v_dl << 4);       // VT: pre-swizzled byte col
  int cgk = (lane >> 4) & 3;                        // K: 4-row chunk sub-row

  // ---- staging pointers: computed once, advanced by constants per tile ----
  const unsigned short* kptr[4];
  const unsigned short* vptr[4];
  #pragma unroll
  for (int j=0;j<4;++j){
    int ch = wave*4 + j;
    int row = ch*4 + cgk;
    int srcb = ((lane & 15)*16) ^ ((row & 7) << 4);
    kptr[j] = kgl + (size_t)row*NQKV + (srcb >> 1);
    int d = ch*8 + v_dl;
    vptr[j] = vtg + (size_t)d*LSEQ + (v_srcb >> 1);
    // prologue: stage K(0), VT(0) into buf 0
    gload_lds16(kptr[j], (char*)Ks[0] + ch*1024);
    gload_lds16(vptr[j], (char*)VTs[0] + ch*1024);
    kptr[j] += 64*NQKV;
    vptr[j] += 64;
  }

  const int NT = LSEQ/64;
  for (int t = 0; t < NT; ++t){
    int cur = t & 1;
    __syncthreads();   // drains tile-t gloads; guards buf[cur^1] overwrite

    // ---- issue K(t+1), VT(t+1) into alt buffers (pointer increments only) ----
    if (t+1 < NT){
      #pragma unroll
      for (int j=0;j<4;++j){
        int ch = wave*4 + j;
        gload_lds16(kptr[j], (char*)Ks[cur^1] + ch*1024);
        gload_lds16(vptr[j], (char*)VTs[cur^1] + ch*1024);
        kptr[j] += 64*NQKV;
        vptr[j] += 64;
      }
    }

    const char* kb = (const char*)Ks[cur];
    const char* vb = (const char*)VTs[cur];

    // ---- QK^T swapped: S^T[kv][q] = mfma32(K, Q); lane: q=ql, kv rows ----
    f32x16 s0 = z16, s1 = z16;
    __builtin_amdgcn_s_setprio(1);
    #pragma unroll
    for (int st=0;st<8;++st){
      int col = (hf*16 + st*32) ^ key;
      short8 kf0 = *(const short8*)(kb + ql*256 + col);          // kv rows 0-31
      short8 kf1 = *(const short8*)(kb + ql*256 + 8192 + col);   // kv rows 32-63
      s0 = __builtin_amdgcn_mfma_f32_32x32x16_bf16(kf0, qf[st], s0, 0,0,0);
      s1 = __builtin_amdgcn_mfma_f32_32x32x16_bf16(kf1, qf[st], s1, 0,0,0);
    }
    __builtin_amdgcn_s_setprio(0);

    // ---- static-max softmax: P = exp2(S) (K2 pre-folded into K; RMSNorm
    // bounds |S| <= ~16.6 in log2 domain -> no overflow) ----
    #pragma unroll
    for (int i=0;i<16;++i) s0[i] = exp2f(s0[i]);
    #pragma unroll
    for (int i=0;i<16;++i) s1[i] = exp2f(s1[i]);

    // ---- P -> A-frags in-register (cvt_pk + permlane32_swap), then PV + l ----
    __builtin_amdgcn_s_setprio(1);
    #pragma unroll
    for (int c=0;c<4;++c){
      unsigned c01, c23, c45, c67;
      if (c < 2){
        int rb = (c&1)*8;
        asm("v_cvt_pk_bf16_f32 %0, %1, %2" : "=v"(c01) : "v"(s0[rb+0]), "v"(s0[rb+1]));
        asm("v_cvt_pk_bf16_f32 %0, %1, %2" : "=v"(c23) : "v"(s0[rb+2]), "v"(s0[rb+3]));
        asm("v_cvt_pk_bf16_f32 %0, %1, %2" : "=v"(c45) : "v"(s0[rb+4]), "v"(s0[rb+5]));
        asm("v_cvt_pk_bf16_f32 %0, %1, %2" : "=v"(c67) : "v"(s0[rb+6]), "v"(s0[rb+7]));
      } else {
        int rb = (c&1)*8;
        asm("v_cvt_pk_bf16_f32 %0, %1, %2" : "=v"(c01) : "v"(s1[rb+0]), "v"(s1[rb+1]));
        asm("v_cvt_pk_bf16_f32 %0, %1, %2" : "=v"(c23) : "v"(s1[rb+2]), "v"(s1[rb+3]));
        asm("v_cvt_pk_bf16_f32 %0, %1, %2" : "=v"(c45) : "v"(s1[rb+4]), "v"(s1[rb+5]));
        asm("v_cvt_pk_bf16_f32 %0, %1, %2" : "=v"(c67) : "v"(s1[rb+6]), "v"(s1[rb+7]));
      }
      // swap: c01.hi <-> c45.lo ; c23.hi <-> c67.lo
      asm("v_permlane32_swap_b32 %0, %1" : "+v"(c01), "+v"(c45));
      asm("v_permlane32_swap_b32 %0, %1" : "+v"(c23), "+v"(c67));
      union { unsigned u[4]; short8 v; } pu;
      pu.u[0] = c01; pu.u[1] = c23; pu.u[2] = c45; pu.u[3] = c67;
      short8 pa = pu.v;   // A[q=ql][kv = c*16 + hf*8 + e]
      accl = __builtin_amdgcn_mfma_f32_32x32x16_bf16(pa, ones, accl, 0,0,0);
      #pragma unroll
      for (int dt=0;dt<4;++dt){
        int col = (c*32 + hf*16) ^ key;
        short8 vf = *(const short8*)(vb + (dt*32 + ql)*128 + col);
        acc[dt] = __builtin_amdgcn_mfma_f32_32x32x16_bf16(pa, vf, acc[dt], 0,0,0);
      }
    }
    __builtin_amdgcn_s_setprio(0);
  }

  // ---- epilogue: accl[r] holds l for q-row rowmap(r) (all lanes) ----
  float rr[16];
  #pragma unroll
  for (int r=0;r<16;++r) rr[r] = 1.f / accl[r];
  size_t qbase = (size_t)(b*LSEQ + q0 + wave*32);
  #pragma unroll
  for (int dt=0;dt<4;++dt){
    int col = h*HDIM + dt*32 + ql;
    #pragma unroll
    for (int r=0;r<16;++r){
      int qrow = (r&3) + 8*(r>>2) + 4*hf;
      o[(qbase + qrow)*DMODEL + col] = f2bf(acc[dt][r]*rr[r]);
    }
  }
}

extern "C" void kernel_launch(void* const* d_in, const int* in_sizes, int n_in,
                              void* d_out, int out_size, void* d_ws, size_t ws_size,
                              hipStream_t stream) {
  const float* x    = (const float*)d_in[0];
  const float* fcos = (const float*)d_in[1];
  const float* fsin = (const float*)d_in[2];
  const float* wqkv = (const float*)d_in[3];
  const float* bqkv = (const float*)d_in[4];
  const float* gq   = (const float*)d_in[5];
  const float* gk   = (const float*)d_in[6];
  const float* wout = (const float*)d_in[7];
  const float* bout = (const float*)d_in[8];
  float* out = (float*)d_out;

  char* ws = (char*)d_ws;
  unsigned short* xb    = (unsigned short*)(ws);                       // 16MB: x bf16, reused as vT
  unsigned short* qkv   = (unsigned short*)(ws + (16ull<<20));         // 48MB: qkv bf16
  unsigned short* ob    = (unsigned short*)(ws + (64ull<<20));         // 16MB: o bf16
  unsigned short* wqkvT = (unsigned short*)(ws + (80ull<<20));         // 6MB
  unsigned short* woutT = (unsigned short*)(ws + (86ull<<20));         // 2MB
  unsigned short* vT    = xb;                                          // alias: xb dead after GEMM1

  k_cvt<<<4096, 256, 0, stream>>>(x, xb, (MTOT*DMODEL)/8);
  k_transpose_cvt<<<dim3(96,32), 256, 0, stream>>>(wqkv, wqkvT, DMODEL, NQKV);
  k_transpose_cvt<<<dim3(32,32), 256, 0, stream>>>(wout, woutT, DMODEL, DMODEL);
  k_gemm_bt<1><<<dim3(NQKV/128, MTOT/128), 256, 0, stream>>>(xb, wqkvT, bqkv, qkv, MTOT, NQKV, DMODEL);
  k_norm_rope<<<MTOT, 256, 0, stream>>>(qkv, fcos, fsin, gq, gk);
  k_vT<<<dim3(LSEQ/32, HDIM/32, 16), 256, 0, stream>>>(qkv, vT);
  k_attn<<<dim3(LSEQ/128, 16), 256, 0, stream>>>(qkv, vT, ob);
  k_gemm_bt<0><<<dim3(DMODEL/128, MTOT/128), 256, 0, stream>>>(ob, woutT, bout, out, MTOT, DMODEL, DMODEL);
}

// Round 16
// 280.487 us; speedup vs baseline: 1.0090x; 1.0090x over previous
//
#include <hip/hip_runtime.h>
#include <hip/hip_bf16.h>
#include <stdint.h>

typedef __attribute__((ext_vector_type(8))) short short8;
typedef __attribute__((ext_vector_type(4))) short short4v;
typedef __attribute__((ext_vector_type(4))) float f32x4;
typedef __attribute__((ext_vector_type(16))) float f32x16;

#define LSEQ 4096
#define DMODEL 1024
#define NHEAD 8
#define HDIM 128
#define MTOT 8192
#define NQKV 3072

__device__ __forceinline__ unsigned short f2bf(float f){
  unsigned u = __float_as_uint(f);
  u += 0x7fffu + ((u >> 16) & 1u);
  return (unsigned short)(u >> 16);
}
__device__ __forceinline__ float bf2f(unsigned short h){
  return __uint_as_float(((unsigned)h) << 16);
}

typedef const __attribute__((address_space(1))) void* gas_ptr;
typedef __attribute__((address_space(3))) void* las_ptr;
__device__ __forceinline__ void gload_lds16(const void* g, void* l){
  __builtin_amdgcn_global_load_lds((gas_ptr)(uintptr_t)g,
                                   (las_ptr)(unsigned)(uintptr_t)l, 16, 0, 0);
}

// ---------------- fp32 -> bf16 cast (8 elems/thread) ----------------
__global__ __launch_bounds__(256) void k_cvt(const float* __restrict__ in,
                                             unsigned short* __restrict__ out, int n8){
  int i = blockIdx.x*256 + threadIdx.x;
  if (i >= n8) return;
  const float4* p = (const float4*)in + (size_t)i*2;
  float4 a = p[0], b = p[1];
  short8 r;
  r[0]=(short)f2bf(a.x); r[1]=(short)f2bf(a.y); r[2]=(short)f2bf(a.z); r[3]=(short)f2bf(a.w);
  r[4]=(short)f2bf(b.x); r[5]=(short)f2bf(b.y); r[6]=(short)f2bf(b.z); r[7]=(short)f2bf(b.w);
  *(short8*)(out + (size_t)i*8) = r;
}

// ---------------- fp32 [R][C] -> bf16 transposed [C][R] ----------------
__global__ __launch_bounds__(256) void k_transpose_cvt(const float* __restrict__ in,
                                                       unsigned short* __restrict__ out,
                                                       int R, int C){
  __shared__ unsigned short tile[32][33];
  int c0 = blockIdx.x*32, r0 = blockIdx.y*32;
  int tx = threadIdx.x & 31, ty = threadIdx.x >> 5;   // 32 x 8
  #pragma unroll
  for (int i=0;i<32;i+=8)
    tile[ty+i][tx] = f2bf(in[(size_t)(r0+ty+i)*C + c0+tx]);
  __syncthreads();
  #pragma unroll
  for (int i=0;i<32;i+=8)
    out[(size_t)(c0+ty+i)*R + r0+tx] = tile[tx][ty+i];
}

// ---------------- bf16 V -> V^T per head: vT[bh][d][l] ----------------
__global__ __launch_bounds__(256) void k_vT(const unsigned short* __restrict__ qkv,
                                            unsigned short* __restrict__ vT){
  __shared__ unsigned short tile[32][33];
  int bh = blockIdx.z; int b = bh >> 3, h = bh & 7;
  int l0 = blockIdx.x*32, d0 = blockIdx.y*32;
  const unsigned short* src = qkv + (size_t)b*LSEQ*NQKV + 2*DMODEL + h*HDIM;
  int tx = threadIdx.x & 31, ty = threadIdx.x >> 5;   // 32 x 8
  #pragma unroll
  for (int i=0;i<32;i+=8)
    tile[ty+i][tx] = src[(size_t)(l0+ty+i)*NQKV + d0+tx];
  __syncthreads();
  unsigned short* dst = vT + ((size_t)bh*HDIM + d0)*LSEQ + l0;
  #pragma unroll
  for (int i=0;i<32;i+=8)
    dst[(size_t)(ty+i)*LSEQ + tx] = tile[tx][ty+i];
}

// ---------------- bf16 GEMM: C[M][N] = A[M][K] * Bt[N][K]^T + bias ----------------
// XCD-aware bijective block swizzle (grid size must be %8==0: 1536 and 512 are)
template<int OUT_BF16>
__global__ __launch_bounds__(256) void k_gemm_bt(const unsigned short* __restrict__ A,
                                                 const unsigned short* __restrict__ Bt,
                                                 const float* __restrict__ bias,
                                                 void* __restrict__ Cout,
                                                 int M, int N, int K){
  __shared__ unsigned short As[128*64];
  __shared__ unsigned short Bs[128*64];
  int tid = threadIdx.x, lane = tid & 63, wave = tid >> 6;
  int wm = wave >> 1, wn = wave & 1;
  // XCD swizzle: contiguous chunks of the linear id land on one XCD
  int nbx = N >> 7;
  int nwg = nbx * (M >> 7);
  int id  = blockIdx.y * nbx + blockIdx.x;
  int cpx = nwg >> 3;
  int swz = (id & 7) * cpx + (id >> 3);
  int m0 = (swz / nbx) * 128, n0 = (swz % nbx) * 128;
  f32x4 zero = {0.f,0.f,0.f,0.f};
  f32x4 acc[4][4];
  #pragma unroll
  for (int mi=0;mi<4;++mi)
    #pragma unroll
    for (int ni=0;ni<4;++ni) acc[mi][ni] = zero;

  int srow = lane >> 3;
  int soffb = (lane & 7) * 16;
  int scol = (soffb ^ (srow << 4)) >> 1;
  int cg = lane >> 4, cl = lane & 15;

  int nkt = K >> 6;
  for (int kt = 0; kt < nkt; ++kt){
    if (kt) __syncthreads();
    int kbase = kt*64;
    #pragma unroll
    for (int j=0;j<4;++j){
      int ch = wave*4 + j;
      int row = ch*8 + srow;
      gload_lds16(A  + (size_t)(m0+row)*K + kbase + scol, (char*)As + ch*1024);
      gload_lds16(Bt + (size_t)(n0+row)*K + kbase + scol, (char*)Bs + ch*1024);
    }
    __syncthreads();

    short8 af[4][2], bf[4][2];
    #pragma unroll
    for (int mi=0;mi<4;++mi){
      int row = wm*64 + mi*16 + cl;
      int key = (row & 7) << 4;
      #pragma unroll
      for (int kk=0;kk<2;++kk)
        af[mi][kk] = *(const short8*)((const char*)As + row*128 + ((kk*64 + cg*16) ^ key));
    }
    #pragma unroll
    for (int ni=0;ni<4;++ni){
      int row = wn*64 + ni*16 + cl;
      int key = (row & 7) << 4;
      #pragma unroll
      for (int kk=0;kk<2;++kk)
        bf[ni][kk] = *(const short8*)((const char*)Bs + row*128 + ((kk*64 + cg*16) ^ key));
    }
    #pragma unroll
    for (int kk=0;kk<2;++kk)
      #pragma unroll
      for (int mi=0;mi<4;++mi)
        #pragma unroll
        for (int ni=0;ni<4;++ni)
          acc[mi][ni] = __builtin_amdgcn_mfma_f32_16x16x32_bf16(af[mi][kk], bf[ni][kk], acc[mi][ni], 0,0,0);
  }

  #pragma unroll
  for (int ni=0;ni<4;++ni){
    int col = n0 + wn*64 + ni*16 + cl;
    float bv = bias[col];
    #pragma unroll
    for (int mi=0;mi<4;++mi){
      int r = m0 + wm*64 + mi*16 + cg*4;
      #pragma unroll
      for (int i=0;i<4;++i){
        float v = acc[mi][ni][i] + bv;
        if (OUT_BF16) ((unsigned short*)Cout)[(size_t)(r+i)*N + col] = f2bf(v);
        else          ((float*)Cout)[(size_t)(r+i)*N + col] = v;
      }
    }
  }
}

// ---------------- fused RMSNorm(q,k) + interleaved RoPE ----------------
// k pre-scaled by K2 = log2(e)/sqrt(128): attention computes P = exp2(S) directly
__global__ __launch_bounds__(256) void k_norm_rope(unsigned short* __restrict__ qkv,
                                                   const float* __restrict__ fcos,
                                                   const float* __restrict__ fsin,
                                                   const float* __restrict__ gq,
                                                   const float* __restrict__ gk){
  int bl = blockIdx.x;
  int l = bl & (LSEQ-1);
  int t = threadIdx.x;
  unsigned short* row = qkv + (size_t)bl * NQKV;
  int d0 = t*4;
  short4v qv = *(short4v*)(row + d0);
  short4v kv = *(short4v*)(row + DMODEL + d0);
  float q[4], k[4];
  #pragma unroll
  for (int j=0;j<4;++j){ q[j] = bf2f((unsigned short)qv[j]); k[j] = bf2f((unsigned short)kv[j]); }
  float sq = q[0]*q[0]+q[1]*q[1]+q[2]*q[2]+q[3]*q[3];
  float sk = k[0]*k[0]+k[1]*k[1]+k[2]*k[2]+k[3]*k[3];
  #pragma unroll
  for (int o=32;o;o>>=1){ sq += __shfl_xor(sq,o); sk += __shfl_xor(sk,o); }
  __shared__ float red[8];
  int lane = t & 63, wv = t >> 6;
  if (!lane){ red[wv] = sq; red[4+wv] = sk; }
  __syncthreads();
  sq = red[0]+red[1]+red[2]+red[3];
  sk = red[4]+red[5]+red[6]+red[7];
  const float K2 = 0.12753568849800323f;    // (1/sqrt(128)) * log2(e)
  float rq = rsqrtf(sq*(1.f/1024.f) + 1e-6f);
  float rk = rsqrtf(sk*(1.f/1024.f) + 1e-6f) * K2;
  int hd = d0 & (HDIM-1);
  int fi = (l << 6) + (hd >> 1);
  float c0 = fcos[fi], s0 = fsin[fi], c1 = fcos[fi+1], s1 = fsin[fi+1];
  {
    float x1 = q[0]*rq*gq[d0],   x2 = q[1]*rq*gq[d0+1];
    float x3 = q[2]*rq*gq[d0+2], x4 = q[3]*rq*gq[d0+3];
    short4v qo;
    qo[0]=(short)f2bf(x1*c0 - x2*s0); qo[1]=(short)f2bf(x1*s0 + x2*c0);
    qo[2]=(short)f2bf(x3*c1 - x4*s1); qo[3]=(short)f2bf(x3*s1 + x4*c1);
    *(short4v*)(row + d0) = qo;
  }
  {
    float x1 = k[0]*rk*gk[d0],   x2 = k[1]*rk*gk[d0+1];
    float x3 = k[2]*rk*gk[d0+2], x4 = k[3]*rk*gk[d0+3];
    short4v ko;
    ko[0]=(short)f2bf(x1*c0 - x2*s0); ko[1]=(short)f2bf(x1*s0 + x2*c0);
    ko[2]=(short)f2bf(x3*c1 - x4*s1); ko[3]=(short)f2bf(x3*s1 + x4*c1);
    *(short4v*)(row + DMODEL + d0) = ko;
  }
}

// ---------------- flash attention v15: software-pipelined tile body —
// QK-s1 MFMAs interleaved with exp2(s0); PV c=0,1 (s0) interleaved with
// exp2(s1); PV c=2,3 (s1). Static-max softmax, K2 folded into K. ----------------
__global__ __launch_bounds__(256, 2) void k_attn(const unsigned short* __restrict__ qkv,
                                                 const unsigned short* __restrict__ vT,
                                                 unsigned short* __restrict__ o){
  __shared__ unsigned short Ks[2][64*128];   // 32KB, rows 256B, XOR-swizzled content
  __shared__ unsigned short VTs[2][128*64];  // 32KB, rows=d 128B, XOR-swizzled content
  int bh = blockIdx.y; int b = bh >> 3, h = bh & 7;
  int q0 = blockIdx.x * 128;
  int tid = threadIdx.x, lane = tid & 63, wave = tid >> 6;
  int ql = lane & 31, hf = lane >> 5;
  const unsigned short* base = qkv + (size_t)b*LSEQ*NQKV + h*HDIM;
  const unsigned short* kgl = base + DMODEL;
  const unsigned short* vtg = vT + (size_t)bh*HDIM*LSEQ;   // [d][l]

  // Q B-frags: lane holds Q[q = ql][d = st*16 + hf*8 + e], st=0..7
  short8 qf[8];
  {
    const unsigned short* qr = base + (size_t)(q0 + wave*32 + ql)*NQKV + hf*8;
    #pragma unroll
    for (int st=0;st<8;++st) qf[st] = *(const short8*)(qr + st*16);
  }
  short8 ones;
  #pragma unroll
  for (int j=0;j<8;++j) ones[j] = (short)0x3F80;   // bf16 1.0

  f32x16 z16 = {0.f};
  f32x16 acc[4];
  acc[0]=z16; acc[1]=z16; acc[2]=z16; acc[3]=z16;
  f32x16 accl = z16;                         // row-sums l (MFMA-ones)

  int key = (ql & 7) << 4;

  int v_dl   = lane >> 3;                           // VT: d within 8-row chunk
  int v_srcb = ((lane & 7)*16) ^ (v_dl << 4);       // VT: pre-swizzled byte col
  int cgk = (lane >> 4) & 3;                        // K: 4-row chunk sub-row

  // ---- staging pointers: computed once, advanced by constants per tile ----
  const unsigned short* kptr[4];
  const unsigned short* vptr[4];
  #pragma unroll
  for (int j=0;j<4;++j){
    int ch = wave*4 + j;
    int row = ch*4 + cgk;
    int srcb = ((lane & 15)*16) ^ ((row & 7) << 4);
    kptr[j] = kgl + (size_t)row*NQKV + (srcb >> 1);
    int d = ch*8 + v_dl;
    vptr[j] = vtg + (size_t)d*LSEQ + (v_srcb >> 1);
    // prologue: stage K(0), VT(0) into buf 0
    gload_lds16(kptr[j], (char*)Ks[0] + ch*1024);
    gload_lds16(vptr[j], (char*)VTs[0] + ch*1024);
    kptr[j] += 64*NQKV;
    vptr[j] += 64;
  }

  const int NT = LSEQ/64;
  for (int t = 0; t < NT; ++t){
    int cur = t & 1;
    __syncthreads();   // drains tile-t gloads; guards buf[cur^1] overwrite

    // ---- issue K(t+1), VT(t+1) into alt buffers (pointer increments only) ----
    if (t+1 < NT){
      #pragma unroll
      for (int j=0;j<4;++j){
        int ch = wave*4 + j;
        gload_lds16(kptr[j], (char*)Ks[cur^1] + ch*1024);
        gload_lds16(vptr[j], (char*)VTs[cur^1] + ch*1024);
        kptr[j] += 64*NQKV;
        vptr[j] += 64;
      }
    }

    const char* kb = (const char*)Ks[cur];
    const char* vb = (const char*)VTs[cur];

    __builtin_amdgcn_s_setprio(1);
    // ---- phase 1: QK^T s0 half (kv rows 0-31), 8 MFMA ----
    f32x16 s0 = z16, s1 = z16;
    #pragma unroll
    for (int st=0;st<8;++st){
      int col = (hf*16 + st*32) ^ key;
      short8 kf0 = *(const short8*)(kb + ql*256 + col);
      s0 = __builtin_amdgcn_mfma_f32_32x32x16_bf16(kf0, qf[st], s0, 0,0,0);
    }
    // ---- phase 2: QK^T s1 half (kv rows 32-63) interleaved with exp2(s0) ----
    #pragma unroll
    for (int st=0;st<8;++st){
      int col = (hf*16 + st*32) ^ key;
      short8 kf1 = *(const short8*)(kb + ql*256 + 8192 + col);
      s1 = __builtin_amdgcn_mfma_f32_32x32x16_bf16(kf1, qf[st], s1, 0,0,0);
      s0[2*st]   = exp2f(s0[2*st]);
      s0[2*st+1] = exp2f(s0[2*st+1]);
    }
    // ---- phase 3: PV c=0,1 (consumes s0) interleaved with exp2(s1) ----
    #pragma unroll
    for (int c=0;c<2;++c){
      unsigned c01, c23, c45, c67;
      int rb = c*8;
      asm("v_cvt_pk_bf16_f32 %0, %1, %2" : "=v"(c01) : "v"(s0[rb+0]), "v"(s0[rb+1]));
      asm("v_cvt_pk_bf16_f32 %0, %1, %2" : "=v"(c23) : "v"(s0[rb+2]), "v"(s0[rb+3]));
      asm("v_cvt_pk_bf16_f32 %0, %1, %2" : "=v"(c45) : "v"(s0[rb+4]), "v"(s0[rb+5]));
      asm("v_cvt_pk_bf16_f32 %0, %1, %2" : "=v"(c67) : "v"(s0[rb+6]), "v"(s0[rb+7]));
      asm("v_permlane32_swap_b32 %0, %1" : "+v"(c01), "+v"(c45));
      asm("v_permlane32_swap_b32 %0, %1" : "+v"(c23), "+v"(c67));
      union { unsigned u[4]; short8 v; } pu;
      pu.u[0] = c01; pu.u[1] = c23; pu.u[2] = c45; pu.u[3] = c67;
      short8 pa = pu.v;   // A[q=ql][kv = c*16 + hf*8 + e]
      // exp2 of s1 chunk (needed by c+2 later) — fills VALU while MFMAs run
      s1[rb+0] = exp2f(s1[rb+0]); s1[rb+1] = exp2f(s1[rb+1]);
      s1[rb+2] = exp2f(s1[rb+2]); s1[rb+3] = exp2f(s1[rb+3]);
      s1[rb+4] = exp2f(s1[rb+4]); s1[rb+5] = exp2f(s1[rb+5]);
      s1[rb+6] = exp2f(s1[rb+6]); s1[rb+7] = exp2f(s1[rb+7]);
      accl = __builtin_amdgcn_mfma_f32_32x32x16_bf16(pa, ones, accl, 0,0,0);
      #pragma unroll
      for (int dt=0;dt<4;++dt){
        int col = (c*32 + hf*16) ^ key;
        short8 vf = *(const short8*)(vb + (dt*32 + ql)*128 + col);
        acc[dt] = __builtin_amdgcn_mfma_f32_32x32x16_bf16(pa, vf, acc[dt], 0,0,0);
      }
    }
    // ---- phase 4: PV c=2,3 (consumes s1) ----
    #pragma unroll
    for (int c=2;c<4;++c){
      unsigned c01, c23, c45, c67;
      int rb = (c&1)*8;
      asm("v_cvt_pk_bf16_f32 %0, %1, %2" : "=v"(c01) : "v"(s1[rb+0]), "v"(s1[rb+1]));
      asm("v_cvt_pk_bf16_f32 %0, %1, %2" : "=v"(c23) : "v"(s1[rb+2]), "v"(s1[rb+3]));
      asm("v_cvt_pk_bf16_f32 %0, %1, %2" : "=v"(c45) : "v"(s1[rb+4]), "v"(s1[rb+5]));
      asm("v_cvt_pk_bf16_f32 %0, %1, %2" : "=v"(c67) : "v"(s1[rb+6]), "v"(s1[rb+7]));
      asm("v_permlane32_swap_b32 %0, %1" : "+v"(c01), "+v"(c45));
      asm("v_permlane32_swap_b32 %0, %1" : "+v"(c23), "+v"(c67));
      union { unsigned u[4]; short8 v; } pu;
      pu.u[0] = c01; pu.u[1] = c23; pu.u[2] = c45; pu.u[3] = c67;
      short8 pa = pu.v;   // A[q=ql][kv = c*16 + hf*8 + e]
      accl = __builtin_amdgcn_mfma_f32_32x32x16_bf16(pa, ones, accl, 0,0,0);
      #pragma unroll
      for (int dt=0;dt<4;++dt){
        int col = (c*32 + hf*16) ^ key;
        short8 vf = *(const short8*)(vb + (dt*32 + ql)*128 + col);
        acc[dt] = __builtin_amdgcn_mfma_f32_32x32x16_bf16(pa, vf, acc[dt], 0,0,0);
      }
    }
    __builtin_amdgcn_s_setprio(0);
  }

  // ---- epilogue: accl[r] holds l for q-row rowmap(r) (all lanes) ----
  float rr[16];
  #pragma unroll
  for (int r=0;r<16;++r) rr[r] = 1.f / accl[r];
  size_t qbase = (size_t)(b*LSEQ + q0 + wave*32);
  #pragma unroll
  for (int dt=0;dt<4;++dt){
    int col = h*HDIM + dt*32 + ql;
    #pragma unroll
    for (int r=0;r<16;++r){
      int qrow = (r&3) + 8*(r>>2) + 4*hf;
      o[(qbase + qrow)*DMODEL + col] = f2bf(acc[dt][r]*rr[r]);
    }
  }
}

extern "C" void kernel_launch(void* const* d_in, const int* in_sizes, int n_in,
                              void* d_out, int out_size, void* d_ws, size_t ws_size,
                              hipStream_t stream) {
  const float* x    = (const float*)d_in[0];
  const float* fcos = (const float*)d_in[1];
  const float* fsin = (const float*)d_in[2];
  const float* wqkv = (const float*)d_in[3];
  const float* bqkv = (const float*)d_in[4];
  const float* gq   = (const float*)d_in[5];
  const float* gk   = (const float*)d_in[6];
  const float* wout = (const float*)d_in[7];
  const float* bout = (const float*)d_in[8];
  float* out = (float*)d_out;

  char* ws = (char*)d_ws;
  unsigned short* xb    = (unsigned short*)(ws);                       // 16MB: x bf16, reused as vT
  unsigned short* qkv   = (unsigned short*)(ws + (16ull<<20));         // 48MB: qkv bf16
  unsigned short* ob    = (unsigned short*)(ws + (64ull<<20));         // 16MB: o bf16
  unsigned short* wqkvT = (unsigned short*)(ws + (80ull<<20));         // 6MB
  unsigned short* woutT = (unsigned short*)(ws + (86ull<<20));         // 2MB
  unsigned short* vT    = xb;                                          // alias: xb dead after GEMM1

  k_cvt<<<4096, 256, 0, stream>>>(x, xb, (MTOT*DMODEL)/8);
  k_transpose_cvt<<<dim3(96,32), 256, 0, stream>>>(wqkv, wqkvT, DMODEL, NQKV);
  k_transpose_cvt<<<dim3(32,32), 256, 0, stream>>>(wout, woutT, DMODEL, DMODEL);
  k_gemm_bt<1><<<dim3(NQKV/128, MTOT/128), 256, 0, stream>>>(xb, wqkvT, bqkv, qkv, MTOT, NQKV, DMODEL);
  k_norm_rope<<<MTOT, 256, 0, stream>>>(qkv, fcos, fsin, gq, gk);
  k_vT<<<dim3(LSEQ/32, HDIM/32, 16), 256, 0, stream>>>(qkv, vT);
  k_attn<<<dim3(LSEQ/128, 16), 256, 0, stream>>>(qkv, vT, ob);
  k_gemm_bt<0><<<dim3(DMODEL/128, MTOT/128), 256, 0, stream>>>(ob, woutT, bout, out, MTOT, DMODEL, DMODEL);
}

// Round 17
// 259.588 us; speedup vs baseline: 1.0902x; 1.0805x over previous
//
#include <hip/hip_runtime.h>
#include <hip/hip_bf16.h>
#include <stdint.h>

typedef __attribute__((ext_vector_type(8))) short short8;
typedef __attribute__((ext_vector_type(4))) short short4v;
typedef __attribute__((ext_vector_type(4))) float f32x4;
typedef __attribute__((ext_vector_type(16))) float f32x16;

#define LSEQ 4096
#define DMODEL 1024
#define NHEAD 8
#define HDIM 128
#define MTOT 8192
#define NQKV 3072

__device__ __forceinline__ unsigned short f2bf(float f){
  unsigned u = __float_as_uint(f);
  u += 0x7fffu + ((u >> 16) & 1u);
  return (unsigned short)(u >> 16);
}
__device__ __forceinline__ float bf2f(unsigned short h){
  return __uint_as_float(((unsigned)h) << 16);
}

typedef const __attribute__((address_space(1))) void* gas_ptr;
typedef __attribute__((address_space(3))) void* las_ptr;
__device__ __forceinline__ void gload_lds16(const void* g, void* l){
  __builtin_amdgcn_global_load_lds((gas_ptr)(uintptr_t)g,
                                   (las_ptr)(unsigned)(uintptr_t)l, 16, 0, 0);
}

// ---------------- fp32 -> bf16 cast (8 elems/thread) ----------------
__global__ __launch_bounds__(256) void k_cvt(const float* __restrict__ in,
                                             unsigned short* __restrict__ out, int n8){
  int i = blockIdx.x*256 + threadIdx.x;
  if (i >= n8) return;
  const float4* p = (const float4*)in + (size_t)i*2;
  float4 a = p[0], b = p[1];
  short8 r;
  r[0]=(short)f2bf(a.x); r[1]=(short)f2bf(a.y); r[2]=(short)f2bf(a.z); r[3]=(short)f2bf(a.w);
  r[4]=(short)f2bf(b.x); r[5]=(short)f2bf(b.y); r[6]=(short)f2bf(b.z); r[7]=(short)f2bf(b.w);
  *(short8*)(out + (size_t)i*8) = r;
}

// ---------------- fp32 [R][C] -> bf16 transposed [C][R] ----------------
__global__ __launch_bounds__(256) void k_transpose_cvt(const float* __restrict__ in,
                                                       unsigned short* __restrict__ out,
                                                       int R, int C){
  __shared__ unsigned short tile[32][33];
  int c0 = blockIdx.x*32, r0 = blockIdx.y*32;
  int tx = threadIdx.x & 31, ty = threadIdx.x >> 5;   // 32 x 8
  #pragma unroll
  for (int i=0;i<32;i+=8)
    tile[ty+i][tx] = f2bf(in[(size_t)(r0+ty+i)*C + c0+tx]);
  __syncthreads();
  #pragma unroll
  for (int i=0;i<32;i+=8)
    out[(size_t)(c0+ty+i)*R + r0+tx] = tile[tx][ty+i];
}

// ---------------- bf16 V -> V^T per head: vT[bh][d][l] ----------------
__global__ __launch_bounds__(256) void k_vT(const unsigned short* __restrict__ qkv,
                                            unsigned short* __restrict__ vT){
  __shared__ unsigned short tile[32][33];
  int bh = blockIdx.z; int b = bh >> 3, h = bh & 7;
  int l0 = blockIdx.x*32, d0 = blockIdx.y*32;
  const unsigned short* src = qkv + (size_t)b*LSEQ*NQKV + 2*DMODEL + h*HDIM;
  int tx = threadIdx.x & 31, ty = threadIdx.x >> 5;   // 32 x 8
  #pragma unroll
  for (int i=0;i<32;i+=8)
    tile[ty+i][tx] = src[(size_t)(l0+ty+i)*NQKV + d0+tx];
  __syncthreads();
  unsigned short* dst = vT + ((size_t)bh*HDIM + d0)*LSEQ + l0;
  #pragma unroll
  for (int i=0;i<32;i+=8)
    dst[(size_t)(ty+i)*LSEQ + tx] = tile[tx][ty+i];
}

// ---------------- bf16 GEMM: C[M][N] = A[M][K] * Bt[N][K]^T + bias ----------------
// XCD-aware bijective block swizzle (grid size must be %8==0: 1536 and 512 are)
template<int OUT_BF16>
__global__ __launch_bounds__(256) void k_gemm_bt(const unsigned short* __restrict__ A,
                                                 const unsigned short* __restrict__ Bt,
                                                 const float* __restrict__ bias,
                                                 void* __restrict__ Cout,
                                                 int M, int N, int K){
  __shared__ unsigned short As[128*64];
  __shared__ unsigned short Bs[128*64];
  int tid = threadIdx.x, lane = tid & 63, wave = tid >> 6;
  int wm = wave >> 1, wn = wave & 1;
  // XCD swizzle: contiguous chunks of the linear id land on one XCD
  int nbx = N >> 7;
  int nwg = nbx * (M >> 7);
  int id  = blockIdx.y * nbx + blockIdx.x;
  int cpx = nwg >> 3;
  int swz = (id & 7) * cpx + (id >> 3);
  int m0 = (swz / nbx) * 128, n0 = (swz % nbx) * 128;
  f32x4 zero = {0.f,0.f,0.f,0.f};
  f32x4 acc[4][4];
  #pragma unroll
  for (int mi=0;mi<4;++mi)
    #pragma unroll
    for (int ni=0;ni<4;++ni) acc[mi][ni] = zero;

  int srow = lane >> 3;
  int soffb = (lane & 7) * 16;
  int scol = (soffb ^ (srow << 4)) >> 1;
  int cg = lane >> 4, cl = lane & 15;

  int nkt = K >> 6;
  for (int kt = 0; kt < nkt; ++kt){
    if (kt) __syncthreads();
    int kbase = kt*64;
    #pragma unroll
    for (int j=0;j<4;++j){
      int ch = wave*4 + j;
      int row = ch*8 + srow;
      gload_lds16(A  + (size_t)(m0+row)*K + kbase + scol, (char*)As + ch*1024);
      gload_lds16(Bt + (size_t)(n0+row)*K + kbase + scol, (char*)Bs + ch*1024);
    }
    __syncthreads();

    short8 af[4][2], bf[4][2];
    #pragma unroll
    for (int mi=0;mi<4;++mi){
      int row = wm*64 + mi*16 + cl;
      int key = (row & 7) << 4;
      #pragma unroll
      for (int kk=0;kk<2;++kk)
        af[mi][kk] = *(const short8*)((const char*)As + row*128 + ((kk*64 + cg*16) ^ key));
    }
    #pragma unroll
    for (int ni=0;ni<4;++ni){
      int row = wn*64 + ni*16 + cl;
      int key = (row & 7) << 4;
      #pragma unroll
      for (int kk=0;kk<2;++kk)
        bf[ni][kk] = *(const short8*)((const char*)Bs + row*128 + ((kk*64 + cg*16) ^ key));
    }
    #pragma unroll
    for (int kk=0;kk<2;++kk)
      #pragma unroll
      for (int mi=0;mi<4;++mi)
        #pragma unroll
        for (int ni=0;ni<4;++ni)
          acc[mi][ni] = __builtin_amdgcn_mfma_f32_16x16x32_bf16(af[mi][kk], bf[ni][kk], acc[mi][ni], 0,0,0);
  }

  #pragma unroll
  for (int ni=0;ni<4;++ni){
    int col = n0 + wn*64 + ni*16 + cl;
    float bv = bias[col];
    #pragma unroll
    for (int mi=0;mi<4;++mi){
      int r = m0 + wm*64 + mi*16 + cg*4;
      #pragma unroll
      for (int i=0;i<4;++i){
        float v = acc[mi][ni][i] + bv;
        if (OUT_BF16) ((unsigned short*)Cout)[(size_t)(r+i)*N + col] = f2bf(v);
        else          ((float*)Cout)[(size_t)(r+i)*N + col] = v;
      }
    }
  }
}

// ---------------- fused RMSNorm(q,k) + interleaved RoPE ----------------
// k pre-scaled by K2 = log2(e)/sqrt(128): attention computes P = exp2(S) directly
__global__ __launch_bounds__(256) void k_norm_rope(unsigned short* __restrict__ qkv,
                                                   const float* __restrict__ fcos,
                                                   const float* __restrict__ fsin,
                                                   const float* __restrict__ gq,
                                                   const float* __restrict__ gk){
  int bl = blockIdx.x;
  int l = bl & (LSEQ-1);
  int t = threadIdx.x;
  unsigned short* row = qkv + (size_t)bl * NQKV;
  int d0 = t*4;
  short4v qv = *(short4v*)(row + d0);
  short4v kv = *(short4v*)(row + DMODEL + d0);
  float q[4], k[4];
  #pragma unroll
  for (int j=0;j<4;++j){ q[j] = bf2f((unsigned short)qv[j]); k[j] = bf2f((unsigned short)kv[j]); }
  float sq = q[0]*q[0]+q[1]*q[1]+q[2]*q[2]+q[3]*q[3];
  float sk = k[0]*k[0]+k[1]*k[1]+k[2]*k[2]+k[3]*k[3];
  #pragma unroll
  for (int o=32;o;o>>=1){ sq += __shfl_xor(sq,o); sk += __shfl_xor(sk,o); }
  __shared__ float red[8];
  int lane = t & 63, wv = t >> 6;
  if (!lane){ red[wv] = sq; red[4+wv] = sk; }
  __syncthreads();
  sq = red[0]+red[1]+red[2]+red[3];
  sk = red[4]+red[5]+red[6]+red[7];
  const float K2 = 0.12753568849800323f;    // (1/sqrt(128)) * log2(e)
  float rq = rsqrtf(sq*(1.f/1024.f) + 1e-6f);
  float rk = rsqrtf(sk*(1.f/1024.f) + 1e-6f) * K2;
  int hd = d0 & (HDIM-1);
  int fi = (l << 6) + (hd >> 1);
  float c0 = fcos[fi], s0 = fsin[fi], c1 = fcos[fi+1], s1 = fsin[fi+1];
  {
    float x1 = q[0]*rq*gq[d0],   x2 = q[1]*rq*gq[d0+1];
    float x3 = q[2]*rq*gq[d0+2], x4 = q[3]*rq*gq[d0+3];
    short4v qo;
    qo[0]=(short)f2bf(x1*c0 - x2*s0); qo[1]=(short)f2bf(x1*s0 + x2*c0);
    qo[2]=(short)f2bf(x3*c1 - x4*s1); qo[3]=(short)f2bf(x3*s1 + x4*c1);
    *(short4v*)(row + d0) = qo;
  }
  {
    float x1 = k[0]*rk*gk[d0],   x2 = k[1]*rk*gk[d0+1];
    float x3 = k[2]*rk*gk[d0+2], x4 = k[3]*rk*gk[d0+3];
    short4v ko;
    ko[0]=(short)f2bf(x1*c0 - x2*s0); ko[1]=(short)f2bf(x1*s0 + x2*c0);
    ko[2]=(short)f2bf(x3*c1 - x4*s1); ko[3]=(short)f2bf(x3*s1 + x4*c1);
    *(short4v*)(row + DMODEL + d0) = ko;
  }
}

// ---------------- flash attention v16: v15 pipeline + raw v_exp_f32
// (__builtin_amdgcn_exp2f; args bounded to ±16.6 by RMSNorm+K2-fold, so the
// OCML denormal-fixup sequence is unnecessary) + raw rcp in epilogue ----------------
__global__ __launch_bounds__(256, 2) void k_attn(const unsigned short* __restrict__ qkv,
                                                 const unsigned short* __restrict__ vT,
                                                 unsigned short* __restrict__ o){
  __shared__ unsigned short Ks[2][64*128];   // 32KB, rows 256B, XOR-swizzled content
  __shared__ unsigned short VTs[2][128*64];  // 32KB, rows=d 128B, XOR-swizzled content
  int bh = blockIdx.y; int b = bh >> 3, h = bh & 7;
  int q0 = blockIdx.x * 128;
  int tid = threadIdx.x, lane = tid & 63, wave = tid >> 6;
  int ql = lane & 31, hf = lane >> 5;
  const unsigned short* base = qkv + (size_t)b*LSEQ*NQKV + h*HDIM;
  const unsigned short* kgl = base + DMODEL;
  const unsigned short* vtg = vT + (size_t)bh*HDIM*LSEQ;   // [d][l]

  // Q B-frags: lane holds Q[q = ql][d = st*16 + hf*8 + e], st=0..7
  short8 qf[8];
  {
    const unsigned short* qr = base + (size_t)(q0 + wave*32 + ql)*NQKV + hf*8;
    #pragma unroll
    for (int st=0;st<8;++st) qf[st] = *(const short8*)(qr + st*16);
  }
  short8 ones;
  #pragma unroll
  for (int j=0;j<8;++j) ones[j] = (short)0x3F80;   // bf16 1.0

  f32x16 z16 = {0.f};
  f32x16 acc[4];
  acc[0]=z16; acc[1]=z16; acc[2]=z16; acc[3]=z16;
  f32x16 accl = z16;                         // row-sums l (MFMA-ones)

  int key = (ql & 7) << 4;

  int v_dl   = lane >> 3;                           // VT: d within 8-row chunk
  int v_srcb = ((lane & 7)*16) ^ (v_dl << 4);       // VT: pre-swizzled byte col
  int cgk = (lane >> 4) & 3;                        // K: 4-row chunk sub-row

  // ---- staging pointers: computed once, advanced by constants per tile ----
  const unsigned short* kptr[4];
  const unsigned short* vptr[4];
  #pragma unroll
  for (int j=0;j<4;++j){
    int ch = wave*4 + j;
    int row = ch*4 + cgk;
    int srcb = ((lane & 15)*16) ^ ((row & 7) << 4);
    kptr[j] = kgl + (size_t)row*NQKV + (srcb >> 1);
    int d = ch*8 + v_dl;
    vptr[j] = vtg + (size_t)d*LSEQ + (v_srcb >> 1);
    // prologue: stage K(0), VT(0) into buf 0
    gload_lds16(kptr[j], (char*)Ks[0] + ch*1024);
    gload_lds16(vptr[j], (char*)VTs[0] + ch*1024);
    kptr[j] += 64*NQKV;
    vptr[j] += 64;
  }

  const int NT = LSEQ/64;
  for (int t = 0; t < NT; ++t){
    int cur = t & 1;
    __syncthreads();   // drains tile-t gloads; guards buf[cur^1] overwrite

    // ---- issue K(t+1), VT(t+1) into alt buffers (pointer increments only) ----
    if (t+1 < NT){
      #pragma unroll
      for (int j=0;j<4;++j){
        int ch = wave*4 + j;
        gload_lds16(kptr[j], (char*)Ks[cur^1] + ch*1024);
        gload_lds16(vptr[j], (char*)VTs[cur^1] + ch*1024);
        kptr[j] += 64*NQKV;
        vptr[j] += 64;
      }
    }

    const char* kb = (const char*)Ks[cur];
    const char* vb = (const char*)VTs[cur];

    __builtin_amdgcn_s_setprio(1);
    // ---- phase 1: QK^T s0 half (kv rows 0-31), 8 MFMA ----
    f32x16 s0 = z16, s1 = z16;
    #pragma unroll
    for (int st=0;st<8;++st){
      int col = (hf*16 + st*32) ^ key;
      short8 kf0 = *(const short8*)(kb + ql*256 + col);
      s0 = __builtin_amdgcn_mfma_f32_32x32x16_bf16(kf0, qf[st], s0, 0,0,0);
    }
    // ---- phase 2: QK^T s1 half (kv rows 32-63) interleaved with exp2(s0) ----
    #pragma unroll
    for (int st=0;st<8;++st){
      int col = (hf*16 + st*32) ^ key;
      short8 kf1 = *(const short8*)(kb + ql*256 + 8192 + col);
      s1 = __builtin_amdgcn_mfma_f32_32x32x16_bf16(kf1, qf[st], s1, 0,0,0);
      s0[2*st]   = __builtin_amdgcn_exp2f(s0[2*st]);
      s0[2*st+1] = __builtin_amdgcn_exp2f(s0[2*st+1]);
    }
    // ---- phase 3: PV c=0,1 (consumes s0) interleaved with exp2(s1) ----
    #pragma unroll
    for (int c=0;c<2;++c){
      unsigned c01, c23, c45, c67;
      int rb = c*8;
      asm("v_cvt_pk_bf16_f32 %0, %1, %2" : "=v"(c01) : "v"(s0[rb+0]), "v"(s0[rb+1]));
      asm("v_cvt_pk_bf16_f32 %0, %1, %2" : "=v"(c23) : "v"(s0[rb+2]), "v"(s0[rb+3]));
      asm("v_cvt_pk_bf16_f32 %0, %1, %2" : "=v"(c45) : "v"(s0[rb+4]), "v"(s0[rb+5]));
      asm("v_cvt_pk_bf16_f32 %0, %1, %2" : "=v"(c67) : "v"(s0[rb+6]), "v"(s0[rb+7]));
      asm("v_permlane32_swap_b32 %0, %1" : "+v"(c01), "+v"(c45));
      asm("v_permlane32_swap_b32 %0, %1" : "+v"(c23), "+v"(c67));
      union { unsigned u[4]; short8 v; } pu;
      pu.u[0] = c01; pu.u[1] = c23; pu.u[2] = c45; pu.u[3] = c67;
      short8 pa = pu.v;   // A[q=ql][kv = c*16 + hf*8 + e]
      // exp2 of s1 chunk (needed by c+2 later) — fills VALU while MFMAs run
      s1[rb+0] = __builtin_amdgcn_exp2f(s1[rb+0]);
      s1[rb+1] = __builtin_amdgcn_exp2f(s1[rb+1]);
      s1[rb+2] = __builtin_amdgcn_exp2f(s1[rb+2]);
      s1[rb+3] = __builtin_amdgcn_exp2f(s1[rb+3]);
      s1[rb+4] = __builtin_amdgcn_exp2f(s1[rb+4]);
      s1[rb+5] = __builtin_amdgcn_exp2f(s1[rb+5]);
      s1[rb+6] = __builtin_amdgcn_exp2f(s1[rb+6]);
      s1[rb+7] = __builtin_amdgcn_exp2f(s1[rb+7]);
      accl = __builtin_amdgcn_mfma_f32_32x32x16_bf16(pa, ones, accl, 0,0,0);
      #pragma unroll
      for (int dt=0;dt<4;++dt){
        int col = (c*32 + hf*16) ^ key;
        short8 vf = *(const short8*)(vb + (dt*32 + ql)*128 + col);
        acc[dt] = __builtin_amdgcn_mfma_f32_32x32x16_bf16(pa, vf, acc[dt], 0,0,0);
      }
    }
    // ---- phase 4: PV c=2,3 (consumes s1) ----
    #pragma unroll
    for (int c=2;c<4;++c){
      unsigned c01, c23, c45, c67;
      int rb = (c&1)*8;
      asm("v_cvt_pk_bf16_f32 %0, %1, %2" : "=v"(c01) : "v"(s1[rb+0]), "v"(s1[rb+1]));
      asm("v_cvt_pk_bf16_f32 %0, %1, %2" : "=v"(c23) : "v"(s1[rb+2]), "v"(s1[rb+3]));
      asm("v_cvt_pk_bf16_f32 %0, %1, %2" : "=v"(c45) : "v"(s1[rb+4]), "v"(s1[rb+5]));
      asm("v_cvt_pk_bf16_f32 %0, %1, %2" : "=v"(c67) : "v"(s1[rb+6]), "v"(s1[rb+7]));
      asm("v_permlane32_swap_b32 %0, %1" : "+v"(c01), "+v"(c45));
      asm("v_permlane32_swap_b32 %0, %1" : "+v"(c23), "+v"(c67));
      union { unsigned u[4]; short8 v; } pu;
      pu.u[0] = c01; pu.u[1] = c23; pu.u[2] = c45; pu.u[3] = c67;
      short8 pa = pu.v;   // A[q=ql][kv = c*16 + hf*8 + e]
      accl = __builtin_amdgcn_mfma_f32_32x32x16_bf16(pa, ones, accl, 0,0,0);
      #pragma unroll
      for (int dt=0;dt<4;++dt){
        int col = (c*32 + hf*16) ^ key;
        short8 vf = *(const short8*)(vb + (dt*32 + ql)*128 + col);
        acc[dt] = __builtin_amdgcn_mfma_f32_32x32x16_bf16(pa, vf, acc[dt], 0,0,0);
      }
    }
    __builtin_amdgcn_s_setprio(0);
  }

  // ---- epilogue: accl[r] holds l for q-row rowmap(r) (all lanes) ----
  float rr[16];
  #pragma unroll
  for (int r=0;r<16;++r) rr[r] = __builtin_amdgcn_rcpf(accl[r]);
  size_t qbase = (size_t)(b*LSEQ + q0 + wave*32);
  #pragma unroll
  for (int dt=0;dt<4;++dt){
    int col = h*HDIM + dt*32 + ql;
    #pragma unroll
    for (int r=0;r<16;++r){
      int qrow = (r&3) + 8*(r>>2) + 4*hf;
      o[(qbase + qrow)*DMODEL + col] = f2bf(acc[dt][r]*rr[r]);
    }
  }
}

extern "C" void kernel_launch(void* const* d_in, const int* in_sizes, int n_in,
                              void* d_out, int out_size, void* d_ws, size_t ws_size,
                              hipStream_t stream) {
  const float* x    = (const float*)d_in[0];
  const float* fcos = (const float*)d_in[1];
  const float* fsin = (const float*)d_in[2];
  const float* wqkv = (const float*)d_in[3];
  const float* bqkv = (const float*)d_in[4];
  const float* gq   = (const float*)d_in[5];
  const float* gk   = (const float*)d_in[6];
  const float* wout = (const float*)d_in[7];
  const float* bout = (const float*)d_in[8];
  float* out = (float*)d_out;

  char* ws = (char*)d_ws;
  unsigned short* xb    = (unsigned short*)(ws);                       // 16MB: x bf16, reused as vT
  unsigned short* qkv   = (unsigned short*)(ws + (16ull<<20));         // 48MB: qkv bf16
  unsigned short* ob    = (unsigned short*)(ws + (64ull<<20));         // 16MB: o bf16
  unsigned short* wqkvT = (unsigned short*)(ws + (80ull<<20));         // 6MB
  unsigned short* woutT = (unsigned short*)(ws + (86ull<<20));         // 2MB
  unsigned short* vT    = xb;                                          // alias: xb dead after GEMM1

  k_cvt<<<4096, 256, 0, stream>>>(x, xb, (MTOT*DMODEL)/8);
  k_transpose_cvt<<<dim3(96,32), 256, 0, stream>>>(wqkv, wqkvT, DMODEL, NQKV);
  k_transpose_cvt<<<dim3(32,32), 256, 0, stream>>>(wout, woutT, DMODEL, DMODEL);
  k_gemm_bt<1><<<dim3(NQKV/128, MTOT/128), 256, 0, stream>>>(xb, wqkvT, bqkv, qkv, MTOT, NQKV, DMODEL);
  k_norm_rope<<<MTOT, 256, 0, stream>>>(qkv, fcos, fsin, gq, gk);
  k_vT<<<dim3(LSEQ/32, HDIM/32, 16), 256, 0, stream>>>(qkv, vT);
  k_attn<<<dim3(LSEQ/128, 16), 256, 0, stream>>>(qkv, vT, ob);
  k_gemm_bt<0><<<dim3(DMODEL/128, MTOT/128), 256, 0, stream>>>(ob, woutT, bout, out, MTOT, DMODEL, DMODEL);
}